// Round 10
// baseline (183.544 us; speedup 1.0000x reference)
//
#include <hip/hip_runtime.h>

typedef unsigned int u32;
typedef unsigned long long u64;

#define BB 16
#define LL 8192
#define CC 512
#define KK 64
#define LCH 256          // L-chunks per batch
#define LPB 32           // rows per chunk (bitmask width)
#define THRESH 2.1f      // survivors/col: mean~146 sigma~12 -> [64,256] w/ ~7 sigma margin

// ---- order-preserving fp32 <-> u32 key transforms ----
__device__ __forceinline__ u32 flip_bits(u32 u) {
  return u ^ ((u & 0x80000000u) ? 0xFFFFFFFFu : 0x80000000u);
}
__device__ __forceinline__ u32 unflip_bits(u32 f) {
  return (f & 0x80000000u) ? (f ^ 0x80000000u) : ~f;
}
__device__ __forceinline__ u64 u64max(u64 a, u64 b) { return a > b ? a : b; }
__device__ __forceinline__ u64 u64min(u64 a, u64 b) { return a < b ? a : b; }

// ---------------- Kernel A (R2-proven): full-row streaming bitmask ----------------
// ATTRIBUTION ROUND (rerun; R9 died to infra): launched 3x (idempotent) so
// dur_total = B + 3A; with the R2 reference total (104us = A + B),
// A = (this_round - 104)/2.
__global__ __launch_bounds__(128) void kbitmask(const float* __restrict__ x,
                                                u32* __restrict__ bm) {
  int blk = blockIdx.x;
  int b = blk >> 8;
  int chunk = blk & (LCH - 1);
  int t = threadIdx.x;
  const float4* p =
      reinterpret_cast<const float4*>(x + ((size_t)b * LL + (size_t)chunk * LPB) * CC) + t;
  u32 m0 = 0, m1 = 0, m2 = 0, m3 = 0;
#pragma unroll
  for (int i = 0; i < LPB; ++i) {
    float4 v = p[(size_t)i * (CC / 4)];
    m0 |= ((u32)(v.x > THRESH)) << i;
    m1 |= ((u32)(v.y > THRESH)) << i;
    m2 |= ((u32)(v.z > THRESH)) << i;
    m3 |= ((u32)(v.w > THRESH)) << i;
  }
  uint4* dst = reinterpret_cast<uint4*>(bm + (size_t)(b * LCH + chunk) * CC) + t;
  *dst = make_uint4(m0, m1, m2, m3);
}

// ---------------- Kernel B (R2-proven): per-column top-64 from bitmasks ----------------
__global__ __launch_bounds__(256) void kselect(const float* __restrict__ x,
                                               const u32* __restrict__ bm,
                                               float* __restrict__ out,
                                               int force_slow) {
  __shared__ u64 lds[4 * 256];
  int lane = threadIdx.x & 63;
  int w = threadIdx.x >> 6;
  int ch = blockIdx.x * 4 + w;
  int b = ch >> 9;
  int c = ch & (CC - 1);
  u64* wl = lds + w * 256;
  const float* colp = x + (size_t)b * LL * CC + c;

#pragma unroll
  for (int r = 0; r < 4; ++r) wl[r * 64 + lane] = 0;
  __syncthreads();

  u32 total = 0;
  if (!force_slow) {
    u32 mk[4];
    u32 cnt = 0;
#pragma unroll
    for (int j = 0; j < 4; ++j) {
      mk[j] = bm[((size_t)(b * LCH) + (u32)(lane * 4 + j)) * CC + c];
      cnt += __popc(mk[j]);
    }
    u32 inc = cnt;
#pragma unroll
    for (int d = 1; d < 64; d <<= 1) {
      u32 o = __shfl_up(inc, d, 64);
      if (lane >= d) inc += o;
    }
    u32 pos = inc - cnt;
    total = __shfl(inc, 63, 64);
#pragma unroll
    for (int j = 0; j < 4; ++j) {
      u32 m = mk[j];
      int base = (lane * 4 + j) * LPB;
      while (m) {
        int bit = __builtin_ctz(m);
        m &= m - 1;
        int l = base + bit;
        float v = colp[(size_t)l * CC];
        u64 key = (((u64)flip_bits(__float_as_uint(v))) << 32) | (u32)l;
        if (pos < 256) wl[pos] = key;
        pos++;
      }
    }
  }
  __syncthreads();

  u64 sel;
  if (!force_slow && total >= (u32)KK && total <= 256u) {
    u64 kk[4];
#pragma unroll
    for (int r = 0; r < 4; ++r) kk[r] = wl[r * 64 + lane];
#pragma unroll
    for (int k = 2; k <= 256; k <<= 1) {
#pragma unroll
      for (int j = k >> 1; j > 0; j >>= 1) {
        if (j >= 64) {
          int rj = j >> 6;
#pragma unroll
          for (int r = 0; r < 4; ++r) {
            int pr = r ^ rj;
            if (pr > r) {
              int e = r * 64 + lane;
              bool descb = ((e & k) == 0);
              u64 a = kk[r], bq = kk[pr];
              u64 mx = u64max(a, bq), mn = u64min(a, bq);
              kk[r] = descb ? mx : mn;
              kk[pr] = descb ? mn : mx;
            }
          }
        } else {
#pragma unroll
          for (int r = 0; r < 4; ++r) {
            u64 other = __shfl_xor(kk[r], j, 64);
            int e = r * 64 + lane;
            bool upper = (lane & j) != 0;
            bool descb = ((e & k) == 0);
            bool keepmax = descb ? !upper : upper;
            kk[r] = keepmax ? u64max(kk[r], other) : u64min(kk[r], other);
          }
        }
      }
    }
    sel = kk[0];
  } else {
    u64 prev = ~0ull;
    sel = 0;
    for (int r = 0; r < KK; ++r) {
      u64 local = 0;
      for (int t = 0; t < LL / 64; ++t) {
        int l = t * 64 + lane;
        float v = colp[(size_t)l * CC];
        u64 key = (((u64)flip_bits(__float_as_uint(v))) << 32) | (u32)l;
        if (key < prev) local = u64max(local, key);
      }
#pragma unroll
      for (int m = 32; m > 0; m >>= 1) local = u64max(local, __shfl_xor(local, m, 64));
      if (lane == r) sel = local;
      prev = local;
    }
  }

  u32 f = (u32)(sel >> 32);
  u32 l = (u32)sel;
  u64 s2 = (((u64)l) << 32) | f;
#pragma unroll
  for (int k = 2; k <= 64; k <<= 1) {
#pragma unroll
    for (int j = k >> 1; j > 0; j >>= 1) {
      u64 other = __shfl_xor(s2, j, 64);
      bool upper = (lane & j) != 0;
      bool ascb = ((lane & k) == 0);
      bool keepmax = ascb ? upper : !upper;
      s2 = keepmax ? u64max(s2, other) : u64min(s2, other);
    }
  }
  float val = __uint_as_float(unflip_bits((u32)s2));
  out[((size_t)b * KK + lane) * CC + c] = val;
}

extern "C" void kernel_launch(void* const* d_in, const int* in_sizes, int n_in,
                              void* d_out, int out_size, void* d_ws, size_t ws_size,
                              hipStream_t stream) {
  const float* x = (const float*)d_in[0];
  float* out = (float*)d_out;
  const size_t need = (size_t)BB * LCH * CC * sizeof(u32);  // 8 MB of bitmasks
  if (d_ws != nullptr && ws_size >= need) {
    u32* bm = (u32*)d_ws;
    // ATTRIBUTION: 3x idempotent A launches -> total = 3A + B; A=(total-104)/2
    kbitmask<<<BB * LCH, 128, 0, stream>>>(x, bm);
    kbitmask<<<BB * LCH, 128, 0, stream>>>(x, bm);
    kbitmask<<<BB * LCH, 128, 0, stream>>>(x, bm);
    kselect<<<(BB * CC) / 4, 256, 0, stream>>>(x, bm, out, 0);
  } else {
    kselect<<<(BB * CC) / 4, 256, 0, stream>>>(x, nullptr, out, 1);
  }
}

// Round 11
// 100.300 us; speedup vs baseline: 1.8300x; 1.8300x over previous
//
#include <hip/hip_runtime.h>

typedef unsigned int u32;
typedef unsigned long long u64;

#define BB 16
#define LL 8192
#define CC 512
#define KK 64
#define LCH 256          // L-chunks per batch
#define LPB 32           // rows per chunk (bitmask width)
#define THRESH 2.1f      // survivors/col: mean~146 sigma~12 -> [64,256] w/ ~7 sigma margin

// ---- order-preserving fp32 <-> u32 key transforms ----
__device__ __forceinline__ u32 flip_bits(u32 u) {
  return u ^ ((u & 0x80000000u) ? 0xFFFFFFFFu : 0x80000000u);
}
__device__ __forceinline__ u32 unflip_bits(u32 f) {
  return (f & 0x80000000u) ? (f ^ 0x80000000u) : ~f;
}
__device__ __forceinline__ u64 u64max(u64 a, u64 b) { return a > b ? a : b; }
__device__ __forceinline__ u64 u64min(u64 a, u64 b) { return a < b ? a : b; }

// ---------------- Kernel A (R2-proven, at roofline ~40us): DO NOT TOUCH ----------------
__global__ __launch_bounds__(128) void kbitmask(const float* __restrict__ x,
                                                u32* __restrict__ bm) {
  int blk = blockIdx.x;
  int b = blk >> 8;
  int chunk = blk & (LCH - 1);
  int t = threadIdx.x;
  const float4* p =
      reinterpret_cast<const float4*>(x + ((size_t)b * LL + (size_t)chunk * LPB) * CC) + t;
  u32 m0 = 0, m1 = 0, m2 = 0, m3 = 0;
#pragma unroll
  for (int i = 0; i < LPB; ++i) {
    float4 v = p[(size_t)i * (CC / 4)];
    m0 |= ((u32)(v.x > THRESH)) << i;
    m1 |= ((u32)(v.y > THRESH)) << i;
    m2 |= ((u32)(v.z > THRESH)) << i;
    m3 |= ((u32)(v.w > THRESH)) << i;
  }
  uint4* dst = reinterpret_cast<uint4*>(bm + (size_t)(b * LCH + chunk) * CC) + t;
  *dst = make_uint4(m0, m1, m2, m3);
}

// ---------------- Kernel B: R2 select with PIPELINED gather ----------------
// Only change vs R2-B (attribution: B ~62us, latency-bound on the divergent
// per-survivor load->vmcnt(0)->ds_write chain): static 8-slot/word bit
// extraction into compile-time-indexed register arrays, then 16 independent
// exec-masked loads per 2-word batch -> 2 latency rounds instead of ~16.
// Overflow (>8 survivors/word) -> exact slow path via ballot.
__global__ __launch_bounds__(256) void kselect(const float* __restrict__ x,
                                               const u32* __restrict__ bm,
                                               float* __restrict__ out,
                                               int force_slow) {
  __shared__ u64 lds[4 * 256];
  int lane = threadIdx.x & 63;
  int w = threadIdx.x >> 6;
  int ch = blockIdx.x * 4 + w;
  int b = ch >> 9;
  int c = ch & (CC - 1);
  u64* wl = lds + w * 256;
  const float* colp = x + (size_t)b * LL * CC + c;

#pragma unroll
  for (int r = 0; r < 4; ++r) wl[r * 64 + lane] = 0;
  __syncthreads();

  u32 total = 0;
  u32 over = 0;
  if (!force_slow) {
    u32 mk[4];
    u32 cnt = 0;
#pragma unroll
    for (int j = 0; j < 4; ++j) {
      mk[j] = bm[((size_t)(b * LCH) + (u32)(lane * 4 + j)) * CC + c];
      cnt += __popc(mk[j]);
    }
    u32 inc = cnt;
#pragma unroll
    for (int d = 1; d < 64; d <<= 1) {
      u32 o = __shfl_up(inc, d, 64);
      if (lane >= d) inc += o;
    }
    u32 pos = inc - cnt;
    total = __shfl(inc, 63, 64);

#pragma unroll
    for (int bp = 0; bp < 2; ++bp) {
      u32 rows_[16];
      float vals_[16];
      u32 vbits = 0;
#pragma unroll
      for (int j = 0; j < 2; ++j) {
        u32 m = mk[bp * 2 + j];
        u32 base = (u32)(lane * 4 + bp * 2 + j) * LPB;
#pragma unroll
        for (int s = 0; s < 8; ++s) {
          u32 bit = __builtin_ctz(m | 0x80000000u);  // 31 when m==0 (slot invalid)
          vbits |= ((m != 0u) ? 1u : 0u) << (j * 8 + s);
          rows_[j * 8 + s] = base + bit;             // static index
          m &= m - 1;
        }
        over |= m;  // nonzero iff word had >8 survivors
      }
      // 16 independent exec-masked loads; issue all, then consume
#pragma unroll
      for (int i = 0; i < 16; ++i)
        vals_[i] = ((vbits >> i) & 1u) ? colp[(size_t)rows_[i] * CC] : 0.0f;
      __builtin_amdgcn_sched_barrier(0);  // keep loads batched above the writes
#pragma unroll
      for (int i = 0; i < 16; ++i) {
        if ((vbits >> i) & 1u) {
          if (pos < 256)
            wl[pos] = (((u64)flip_bits(__float_as_uint(vals_[i]))) << 32) | rows_[i];
          pos++;
        }
      }
    }
  }
  __syncthreads();

  bool fastok = !force_slow && total >= (u32)KK && total <= 256u &&
                (__ballot(over != 0u) == 0ull);
  u64 sel;
  if (fastok) {
    u64 kk[4];
#pragma unroll
    for (int r = 0; r < 4; ++r) kk[r] = wl[r * 64 + lane];
#pragma unroll
    for (int k = 2; k <= 256; k <<= 1) {
#pragma unroll
      for (int j = k >> 1; j > 0; j >>= 1) {
        if (j >= 64) {
          int rj = j >> 6;
#pragma unroll
          for (int r = 0; r < 4; ++r) {
            int pr = r ^ rj;
            if (pr > r) {
              int e = r * 64 + lane;
              bool descb = ((e & k) == 0);
              u64 a = kk[r], bq = kk[pr];
              u64 mx = u64max(a, bq), mn = u64min(a, bq);
              kk[r] = descb ? mx : mn;
              kk[pr] = descb ? mn : mx;
            }
          }
        } else {
#pragma unroll
          for (int r = 0; r < 4; ++r) {
            u64 other = __shfl_xor(kk[r], j, 64);
            int e = r * 64 + lane;
            bool upper = (lane & j) != 0;
            bool descb = ((e & k) == 0);
            bool keepmax = descb ? !upper : upper;
            kk[r] = keepmax ? u64max(kk[r], other) : u64min(kk[r], other);
          }
        }
      }
    }
    sel = kk[0];
  } else {
    // exact slow path: 64 rounds of wave-reduce max over keys < prev
    u64 prev = ~0ull;
    sel = 0;
    for (int r = 0; r < KK; ++r) {
      u64 local = 0;
      for (int t = 0; t < LL / 64; ++t) {
        int l = t * 64 + lane;
        float v = colp[(size_t)l * CC];
        u64 key = (((u64)flip_bits(__float_as_uint(v))) << 32) | (u32)l;
        if (key < prev) local = u64max(local, key);
      }
#pragma unroll
      for (int m = 32; m > 0; m >>= 1) local = u64max(local, __shfl_xor(local, m, 64));
      if (lane == r) sel = local;
      prev = local;
    }
  }

  // re-key by (index, value), sort ASCENDING -> original sequence order
  u32 f = (u32)(sel >> 32);
  u32 l = (u32)sel;
  u64 s2 = (((u64)l) << 32) | f;
#pragma unroll
  for (int k = 2; k <= 64; k <<= 1) {
#pragma unroll
    for (int j = k >> 1; j > 0; j >>= 1) {
      u64 other = __shfl_xor(s2, j, 64);
      bool upper = (lane & j) != 0;
      bool ascb = ((lane & k) == 0);
      bool keepmax = ascb ? upper : !upper;
      s2 = keepmax ? u64max(s2, other) : u64min(s2, other);
    }
  }
  float val = __uint_as_float(unflip_bits((u32)s2));
  out[((size_t)b * KK + lane) * CC + c] = val;
}

extern "C" void kernel_launch(void* const* d_in, const int* in_sizes, int n_in,
                              void* d_out, int out_size, void* d_ws, size_t ws_size,
                              hipStream_t stream) {
  const float* x = (const float*)d_in[0];
  float* out = (float*)d_out;
  const size_t need = (size_t)BB * LCH * CC * sizeof(u32);  // 8 MB of bitmasks
  if (d_ws != nullptr && ws_size >= need) {
    u32* bm = (u32*)d_ws;
    kbitmask<<<BB * LCH, 128, 0, stream>>>(x, bm);
    kselect<<<(BB * CC) / 4, 256, 0, stream>>>(x, bm, out, 0);
  } else {
    kselect<<<(BB * CC) / 4, 256, 0, stream>>>(x, nullptr, out, 1);
  }
}

// Round 12
// 93.773 us; speedup vs baseline: 1.9573x; 1.0696x over previous
//
#include <hip/hip_runtime.h>

typedef unsigned int u32;
typedef unsigned long long u64;

#define BB 16
#define LL 8192
#define CC 512
#define KK 64
#define LCH 256          // L-chunks per batch
#define LPB 32           // rows per chunk (bitmask width)
#define THRESH 2.1f      // survivors/col: mean~146 sigma~12 -> [64,256] w/ ~7 sigma margin

// ---- order-preserving fp32 <-> u32 key transforms ----
__device__ __forceinline__ u32 flip_bits(u32 u) {
  return u ^ ((u & 0x80000000u) ? 0xFFFFFFFFu : 0x80000000u);
}
__device__ __forceinline__ u32 unflip_bits(u32 f) {
  return (f & 0x80000000u) ? (f ^ 0x80000000u) : ~f;
}
__device__ __forceinline__ u64 u64max(u64 a, u64 b) { return a > b ? a : b; }
__device__ __forceinline__ u64 u64min(u64 a, u64 b) { return a < b ? a : b; }

// ---------------- Kernel A (R2-proven, at roofline ~40us): DO NOT TOUCH ----------------
__global__ __launch_bounds__(128) void kbitmask(const float* __restrict__ x,
                                                u32* __restrict__ bm) {
  int blk = blockIdx.x;
  int b = blk >> 8;
  int chunk = blk & (LCH - 1);
  int t = threadIdx.x;
  const float4* p =
      reinterpret_cast<const float4*>(x + ((size_t)b * LL + (size_t)chunk * LPB) * CC) + t;
  u32 m0 = 0, m1 = 0, m2 = 0, m3 = 0;
#pragma unroll
  for (int i = 0; i < LPB; ++i) {
    float4 v = p[(size_t)i * (CC / 4)];
    m0 |= ((u32)(v.x > THRESH)) << i;
    m1 |= ((u32)(v.y > THRESH)) << i;
    m2 |= ((u32)(v.z > THRESH)) << i;
    m3 |= ((u32)(v.w > THRESH)) << i;
  }
  uint4* dst = reinterpret_cast<uint4*>(bm + (size_t)(b * LCH + chunk) * CC) + t;
  *dst = make_uint4(m0, m1, m2, m3);
}

// ---------------- Kernel B: SORT-FREE top-64 select ----------------
// wl[] is filled in ROW ORDER (prefix-scan ranks = row ranks), so no sort is
// needed: bit-build bisection (64 rounds of 4 ballots, no LDS/bpermute traffic
// — R11 post-mortem: the bitonic's ~340 ds_bpermutes were ~23us of LDS pipe)
// finds X = 64th-largest key exactly (keys unique); selection ballots give
// each element its output rank in row order directly. Slow path unchanged.
__global__ __launch_bounds__(256) void kselect(const float* __restrict__ x,
                                               const u32* __restrict__ bm,
                                               float* __restrict__ out,
                                               int force_slow) {
  __shared__ u64 lds[4 * 256];
  int lane = threadIdx.x & 63;
  int w = threadIdx.x >> 6;
  int ch = blockIdx.x * 4 + w;
  int b = ch >> 9;
  int c = ch & (CC - 1);
  u64* wl = lds + w * 256;
  const float* colp = x + (size_t)b * LL * CC + c;
  const u64 ltmask = (1ull << lane) - 1ull;

#pragma unroll
  for (int r = 0; r < 4; ++r) wl[r * 64 + lane] = 0;
  __syncthreads();

  u32 total = 0;
  u32 over = 0;
  if (!force_slow) {
    u32 mk[4];
    u32 cnt = 0;
#pragma unroll
    for (int j = 0; j < 4; ++j) {
      mk[j] = bm[((size_t)(b * LCH) + (u32)(lane * 4 + j)) * CC + c];
      cnt += __popc(mk[j]);
    }
    u32 inc = cnt;
#pragma unroll
    for (int d = 1; d < 64; d <<= 1) {
      u32 o = __shfl_up(inc, d, 64);
      if (lane >= d) inc += o;
    }
    u32 pos = inc - cnt;
    total = __shfl(inc, 63, 64);

    // pipelined gather (R11-proven): static 8 slots/word, 2 batches of 16 loads
#pragma unroll
    for (int bp = 0; bp < 2; ++bp) {
      u32 rows_[16];
      float vals_[16];
      u32 vbits = 0;
#pragma unroll
      for (int j = 0; j < 2; ++j) {
        u32 m = mk[bp * 2 + j];
        u32 base = (u32)(lane * 4 + bp * 2 + j) * LPB;
#pragma unroll
        for (int s = 0; s < 8; ++s) {
          u32 bit = __builtin_ctz(m | 0x80000000u);
          vbits |= ((m != 0u) ? 1u : 0u) << (j * 8 + s);
          rows_[j * 8 + s] = base + bit;
          m &= m - 1;
        }
        over |= m;
      }
#pragma unroll
      for (int i = 0; i < 16; ++i)
        vals_[i] = ((vbits >> i) & 1u) ? colp[(size_t)rows_[i] * CC] : 0.0f;
      __builtin_amdgcn_sched_barrier(0);
#pragma unroll
      for (int i = 0; i < 16; ++i) {
        if ((vbits >> i) & 1u) {
          if (pos < 256)
            wl[pos] = (((u64)flip_bits(__float_as_uint(vals_[i]))) << 32) | rows_[i];
          pos++;
        }
      }
    }
  }
  __syncthreads();

  bool fastok = !force_slow && total >= (u32)KK && total <= 256u &&
                (__ballot(over != 0u) == 0ull);
  if (fastok) {
    u64 kk[4];
#pragma unroll
    for (int r = 0; r < 4; ++r) kk[r] = wl[r * 64 + lane];
    // bit-build bisection: X = largest u64 with cnt_ge(X) >= 64  ==  64th-largest
    // key (keys unique). Invalid entries are 0, excluded since trial >= 1.
    u64 X = 0;
    for (int bit = 63; bit >= 0; --bit) {
      u64 trial = X | (1ull << bit);
      int cnt = __popcll(__ballot(kk[0] >= trial)) + __popcll(__ballot(kk[1] >= trial)) +
                __popcll(__ballot(kk[2] >= trial)) + __popcll(__ballot(kk[3] >= trial));
      if (cnt >= KK) X = trial;
    }
    // selection ballots -> output rank in wl (= row) order; exactly 64 selected
    u64 bal[4];
#pragma unroll
    for (int r = 0; r < 4; ++r) bal[r] = __ballot(kk[r] >= X);
    u32 pref = 0;
#pragma unroll
    for (int r = 0; r < 4; ++r) {
      if (kk[r] >= X) {
        u32 rank = pref + (u32)__popcll(bal[r] & ltmask);
        out[((size_t)b * KK + rank) * CC + c] =
            __uint_as_float(unflip_bits((u32)(kk[r] >> 32)));
      }
      pref += (u32)__popcll(bal[r]);
    }
  } else {
    // exact slow path: 64 rounds of wave-reduce max over keys < prev,
    // then index re-sort (bitonic) — rare, correctness backstop only.
    u64 prev = ~0ull;
    u64 sel = 0;
    for (int r = 0; r < KK; ++r) {
      u64 local = 0;
      for (int t = 0; t < LL / 64; ++t) {
        int l = t * 64 + lane;
        float v = colp[(size_t)l * CC];
        u64 key = (((u64)flip_bits(__float_as_uint(v))) << 32) | (u32)l;
        if (key < prev) local = u64max(local, key);
      }
#pragma unroll
      for (int m = 32; m > 0; m >>= 1) local = u64max(local, __shfl_xor(local, m, 64));
      if (lane == r) sel = local;
      prev = local;
    }
    u32 f = (u32)(sel >> 32);
    u32 l = (u32)sel;
    u64 s2 = (((u64)l) << 32) | f;
#pragma unroll
    for (int k = 2; k <= 64; k <<= 1) {
#pragma unroll
      for (int j = k >> 1; j > 0; j >>= 1) {
        u64 other = __shfl_xor(s2, j, 64);
        bool upper = (lane & j) != 0;
        bool ascb = ((lane & k) == 0);
        bool keepmax = ascb ? upper : !upper;
        s2 = keepmax ? u64max(s2, other) : u64min(s2, other);
      }
    }
    out[((size_t)b * KK + lane) * CC + c] = __uint_as_float(unflip_bits((u32)s2));
  }
}

extern "C" void kernel_launch(void* const* d_in, const int* in_sizes, int n_in,
                              void* d_out, int out_size, void* d_ws, size_t ws_size,
                              hipStream_t stream) {
  const float* x = (const float*)d_in[0];
  float* out = (float*)d_out;
  const size_t need = (size_t)BB * LCH * CC * sizeof(u32);  // 8 MB of bitmasks
  if (d_ws != nullptr && ws_size >= need) {
    u32* bm = (u32*)d_ws;
    kbitmask<<<BB * LCH, 128, 0, stream>>>(x, bm);
    kselect<<<(BB * CC) / 4, 256, 0, stream>>>(x, bm, out, 0);
  } else {
    kselect<<<(BB * CC) / 4, 256, 0, stream>>>(x, nullptr, out, 1);
  }
}

// Round 13
// 82.196 us; speedup vs baseline: 2.2330x; 1.1408x over previous
//
#include <hip/hip_runtime.h>

typedef unsigned int u32;
typedef unsigned long long u64;

#define BB 16
#define LL 8192
#define CC 512
#define KK 64
#define LCH 256          // L-chunks per batch
#define LPB 32           // rows per chunk (bitmask width)
#define THRESH 2.1f      // survivors/col: mean~146 sigma~12 -> [64,256] w/ ~7 sigma margin

// ---- order-preserving fp32 <-> u32 key transforms ----
__device__ __forceinline__ u32 flip_bits(u32 u) {
  return u ^ ((u & 0x80000000u) ? 0xFFFFFFFFu : 0x80000000u);
}
__device__ __forceinline__ u32 unflip_bits(u32 f) {
  return (f & 0x80000000u) ? (f ^ 0x80000000u) : ~f;
}
__device__ __forceinline__ u64 u64max(u64 a, u64 b) { return a > b ? a : b; }
__device__ __forceinline__ u64 u64min(u64 a, u64 b) { return a < b ? a : b; }

// ---------------- Kernel A (R2-proven, at roofline ~40us): DO NOT TOUCH ----------------
__global__ __launch_bounds__(128) void kbitmask(const float* __restrict__ x,
                                                u32* __restrict__ bm) {
  int blk = blockIdx.x;
  int b = blk >> 8;
  int chunk = blk & (LCH - 1);
  int t = threadIdx.x;
  const float4* p =
      reinterpret_cast<const float4*>(x + ((size_t)b * LL + (size_t)chunk * LPB) * CC) + t;
  u32 m0 = 0, m1 = 0, m2 = 0, m3 = 0;
#pragma unroll
  for (int i = 0; i < LPB; ++i) {
    float4 v = p[(size_t)i * (CC / 4)];
    m0 |= ((u32)(v.x > THRESH)) << i;
    m1 |= ((u32)(v.y > THRESH)) << i;
    m2 |= ((u32)(v.z > THRESH)) << i;
    m3 |= ((u32)(v.w > THRESH)) << i;
  }
  uint4* dst = reinterpret_cast<uint4*>(bm + (size_t)(b * LCH + chunk) * CC) + t;
  *dst = make_uint4(m0, m1, m2, m3);
}

// ---------------- Kernel B: one BLOCK (256 thr) per column ----------------
// R12 post-mortem: wave-per-column B serialized every phase at 64-lane width.
// Now: thread t owns mask word t -> whole gather in ONE parallel latency round;
// block scan -> row-ordered keys in wl[256]; selection via rank-by-broadcast-
// counting over LDS (no serial bisection, no bpermute storms); output position
// from 4 per-wave ballots. Exact slow path (wave 0) as backstop.
__global__ __launch_bounds__(256) void kselect(const float* __restrict__ x,
                                               const u32* __restrict__ bm,
                                               float* __restrict__ out,
                                               int force_slow) {
  __shared__ u64 wl[256];
  __shared__ u32 wsum[4];
  __shared__ u64 selbal[4];
  __shared__ int bad;
  int t = threadIdx.x;
  int lane = t & 63;
  int w = t >> 6;
  int ch = blockIdx.x;
  int b = ch >> 9;
  int c = ch & (CC - 1);
  const float* colp = x + (size_t)b * LL * CC + c;
  const u64 ltmask = (1ull << lane) - 1ull;

  if (t == 0) bad = force_slow;
  wl[t] = 0;
  __syncthreads();

  u32 total = 0;
  if (!force_slow) {
    // phase 1: one mask word per thread (parallel uncoalesced round)
    u32 mw = bm[((size_t)(b * LCH) + (u32)t) * CC + c];
    u32 cnt = __popc(mw);
    // phase 2: block exclusive scan (wave scan + cross-wave offsets)
    u32 inc = cnt;
#pragma unroll
    for (int d = 1; d < 64; d <<= 1) {
      u32 o = __shfl_up(inc, d, 64);
      if (lane >= d) inc += o;
    }
    if (lane == 63) wsum[w] = inc;
    __syncthreads();
    u32 woff = 0;
#pragma unroll
    for (int i = 0; i < 4; ++i) {
      u32 s = wsum[i];
      woff += (i < w) ? s : 0u;
      total += s;
    }
    u32 pos = woff + inc - cnt;
    // phase 3: static 8-slot extraction + one batch of independent loads
    u32 rows_[8];
    float vals_[8];
    u32 vbits = 0;
    u32 m = mw;
    u32 base = (u32)t * LPB;
#pragma unroll
    for (int s = 0; s < 8; ++s) {
      u32 bit = __builtin_ctz(m | 0x80000000u);
      vbits |= ((m != 0u) ? 1u : 0u) << s;
      rows_[s] = base + bit;
      m &= m - 1;
    }
    if (m) bad = 1;  // >8 survivors in one word (P ~ 1e-8/word)
#pragma unroll
    for (int s = 0; s < 8; ++s)
      vals_[s] = ((vbits >> s) & 1u) ? colp[(size_t)rows_[s] * CC] : 0.0f;
    __builtin_amdgcn_sched_barrier(0);
    // phase 4: row-ordered key write
#pragma unroll
    for (int s = 0; s < 8; ++s) {
      if ((vbits >> s) & 1u) {
        if (pos < 256)
          wl[pos] = (((u64)flip_bits(__float_as_uint(vals_[s]))) << 32) | rows_[s];
        else
          bad = 1;
        pos++;
      }
    }
  }
  __syncthreads();

  bool fastok = (bad == 0) && total >= (u32)KK && total <= 256u;
  if (fastok) {
    // phase 5: rank by broadcast-counting (keys unique -> strict ranks unique)
    u64 mykey = (t < (int)total) ? wl[t] : 0ull;
    u32 rank = 0;
#pragma unroll 4
    for (u32 j = 0; j < total; ++j) rank += (wl[j] > mykey) ? 1u : 0u;
    bool selp = (t < (int)total) && (rank < (u32)KK);
    // phase 6: output position = selected-count before me (wl order = row order)
    u64 bw = __ballot(selp);
    if (lane == 0) selbal[w] = bw;
    __syncthreads();
    if (selp) {
      u32 op = (u32)__popcll(bw & ltmask);
#pragma unroll
      for (int i = 0; i < 4; ++i) op += (i < w) ? (u32)__popcll(selbal[i]) : 0u;
      out[((size_t)b * KK + op) * CC + c] =
          __uint_as_float(unflip_bits((u32)(mykey >> 32)));
    }
  } else if (w == 0) {
    // exact slow path (wave 0): 64 rounds of wave-reduce max, then index sort
    u64 prev = ~0ull;
    u64 sel = 0;
    for (int r = 0; r < KK; ++r) {
      u64 local = 0;
      for (int tt = 0; tt < LL / 64; ++tt) {
        int l = tt * 64 + lane;
        float v = colp[(size_t)l * CC];
        u64 key = (((u64)flip_bits(__float_as_uint(v))) << 32) | (u32)l;
        if (key < prev) local = u64max(local, key);
      }
#pragma unroll
      for (int mm = 32; mm > 0; mm >>= 1) local = u64max(local, __shfl_xor(local, mm, 64));
      if (lane == r) sel = local;
      prev = local;
    }
    u32 f = (u32)(sel >> 32);
    u32 l = (u32)sel;
    u64 s2 = (((u64)l) << 32) | f;
#pragma unroll
    for (int k = 2; k <= 64; k <<= 1) {
#pragma unroll
      for (int j = k >> 1; j > 0; j >>= 1) {
        u64 other = __shfl_xor(s2, j, 64);
        bool upper = (lane & j) != 0;
        bool ascb = ((lane & k) == 0);
        bool keepmax = ascb ? upper : !upper;
        s2 = keepmax ? u64max(s2, other) : u64min(s2, other);
      }
    }
    out[((size_t)b * KK + lane) * CC + c] = __uint_as_float(unflip_bits((u32)s2));
  }
}

extern "C" void kernel_launch(void* const* d_in, const int* in_sizes, int n_in,
                              void* d_out, int out_size, void* d_ws, size_t ws_size,
                              hipStream_t stream) {
  const float* x = (const float*)d_in[0];
  float* out = (float*)d_out;
  const size_t need = (size_t)BB * LCH * CC * sizeof(u32);  // 8 MB of bitmasks
  if (d_ws != nullptr && ws_size >= need) {
    u32* bm = (u32*)d_ws;
    kbitmask<<<BB * LCH, 128, 0, stream>>>(x, bm);
    kselect<<<BB * CC, 256, 0, stream>>>(x, bm, out, 0);
  } else {
    kselect<<<BB * CC, 256, 0, stream>>>(x, nullptr, out, 1);
  }
}

// Round 14
// 79.991 us; speedup vs baseline: 2.2946x; 1.0276x over previous
//
#include <hip/hip_runtime.h>

typedef unsigned int u32;
typedef unsigned long long u64;

#define BB 16
#define LL 8192
#define CC 512
#define KK 64
#define LCH 256          // L-chunks per batch
#define LPB 32           // rows per chunk (bitmask width)
#define THRESH 2.1f      // survivors/col: mean~146 sigma~12 -> [64,256] w/ ~7 sigma margin

// ---- order-preserving fp32 <-> u32 key transforms ----
__device__ __forceinline__ u32 flip_bits(u32 u) {
  return u ^ ((u & 0x80000000u) ? 0xFFFFFFFFu : 0x80000000u);
}
__device__ __forceinline__ u32 unflip_bits(u32 f) {
  return (f & 0x80000000u) ? (f ^ 0x80000000u) : ~f;
}
__device__ __forceinline__ u64 u64max(u64 a, u64 b) { return a > b ? a : b; }
__device__ __forceinline__ u64 u64min(u64 a, u64 b) { return a < b ? a : b; }

// ---------------- Kernel A (R2-proven, at roofline ~40us): DO NOT TOUCH ----------------
__global__ __launch_bounds__(128) void kbitmask(const float* __restrict__ x,
                                                u32* __restrict__ bm) {
  int blk = blockIdx.x;
  int b = blk >> 8;
  int chunk = blk & (LCH - 1);
  int t = threadIdx.x;
  const float4* p =
      reinterpret_cast<const float4*>(x + ((size_t)b * LL + (size_t)chunk * LPB) * CC) + t;
  u32 m0 = 0, m1 = 0, m2 = 0, m3 = 0;
#pragma unroll
  for (int i = 0; i < LPB; ++i) {
    float4 v = p[(size_t)i * (CC / 4)];
    m0 |= ((u32)(v.x > THRESH)) << i;
    m1 |= ((u32)(v.y > THRESH)) << i;
    m2 |= ((u32)(v.z > THRESH)) << i;
    m3 |= ((u32)(v.w > THRESH)) << i;
  }
  uint4* dst = reinterpret_cast<uint4*>(bm + (size_t)(b * LCH + chunk) * CC) + t;
  *dst = make_uint4(m0, m1, m2, m3);
}

// ---------------- Kernel B: block-per-column (R13) + XCD-colocated groups ----------------
// R13 post-mortem: B's bm read re-fetches each 64B line ~8x (16 same-line
// column-blocks spread over 8 XCDs) and the 76MB single-use gather thrashes
// L2. Fix 1: bijective blockIdx remap so a 16-column line-group shares one
// XCD's L2 (bm ~64->8MB). Fix 2: nontemporal gather loads (don't evict bm).
__global__ __launch_bounds__(256) void kselect(const float* __restrict__ x,
                                               const u32* __restrict__ bm,
                                               float* __restrict__ out,
                                               int force_slow) {
  __shared__ u64 wl[256];
  __shared__ u32 wsum[4];
  __shared__ u64 selbal[4];
  __shared__ int bad;
  int t = threadIdx.x;
  int lane = t & 63;
  int w = t >> 6;
  // XCD-colocating bijection: all 16 blocks of a column line-group get the
  // same (bid & 7) residue -> same XCD (empirical round-robin mapping).
  int bid = blockIdx.x;
  int xcd = bid & 7;
  int iox = bid >> 3;               // 0..1023
  int g = (iox >> 4) * 8 + xcd;     // 0..511 line-group
  int ch = g * 16 + (iox & 15);     // column id, bijective over [0, 8192)
  int b = ch >> 9;
  int c = ch & (CC - 1);
  const float* colp = x + (size_t)b * LL * CC + c;
  const u64 ltmask = (1ull << lane) - 1ull;

  if (t == 0) bad = force_slow;
  wl[t] = 0;
  __syncthreads();

  u32 total = 0;
  if (!force_slow) {
    // phase 1: one mask word per thread (lines shared by the 16-col group)
    u32 mw = bm[((size_t)(b * LCH) + (u32)t) * CC + c];
    u32 cnt = __popc(mw);
    // phase 2: block exclusive scan (wave scan + cross-wave offsets)
    u32 inc = cnt;
#pragma unroll
    for (int d = 1; d < 64; d <<= 1) {
      u32 o = __shfl_up(inc, d, 64);
      if (lane >= d) inc += o;
    }
    if (lane == 63) wsum[w] = inc;
    __syncthreads();
    u32 woff = 0;
#pragma unroll
    for (int i = 0; i < 4; ++i) {
      u32 s = wsum[i];
      woff += (i < w) ? s : 0u;
      total += s;
    }
    u32 pos = woff + inc - cnt;
    // phase 3: static 8-slot extraction + one batch of independent NT loads
    u32 rows_[8];
    float vals_[8];
    u32 vbits = 0;
    u32 m = mw;
    u32 base = (u32)t * LPB;
#pragma unroll
    for (int s = 0; s < 8; ++s) {
      u32 bit = __builtin_ctz(m | 0x80000000u);
      vbits |= ((m != 0u) ? 1u : 0u) << s;
      rows_[s] = base + bit;
      m &= m - 1;
    }
    if (m) bad = 1;  // >8 survivors in one word (P ~ 1e-8/word)
#pragma unroll
    for (int s = 0; s < 8; ++s)
      vals_[s] = ((vbits >> s) & 1u)
                     ? __builtin_nontemporal_load(colp + (size_t)rows_[s] * CC)
                     : 0.0f;
    __builtin_amdgcn_sched_barrier(0);
    // phase 4: row-ordered key write
#pragma unroll
    for (int s = 0; s < 8; ++s) {
      if ((vbits >> s) & 1u) {
        if (pos < 256)
          wl[pos] = (((u64)flip_bits(__float_as_uint(vals_[s]))) << 32) | rows_[s];
        else
          bad = 1;
        pos++;
      }
    }
  }
  __syncthreads();

  bool fastok = (bad == 0) && total >= (u32)KK && total <= 256u;
  if (fastok) {
    // phase 5: rank by broadcast-counting (keys unique -> strict ranks unique)
    u64 mykey = (t < (int)total) ? wl[t] : 0ull;
    u32 rank = 0;
#pragma unroll 4
    for (u32 j = 0; j < total; ++j) rank += (wl[j] > mykey) ? 1u : 0u;
    bool selp = (t < (int)total) && (rank < (u32)KK);
    // phase 6: output position = selected-count before me (wl order = row order)
    u64 bw = __ballot(selp);
    if (lane == 0) selbal[w] = bw;
    __syncthreads();
    if (selp) {
      u32 op = (u32)__popcll(bw & ltmask);
#pragma unroll
      for (int i = 0; i < 4; ++i) op += (i < w) ? (u32)__popcll(selbal[i]) : 0u;
      out[((size_t)b * KK + op) * CC + c] =
          __uint_as_float(unflip_bits((u32)(mykey >> 32)));
    }
  } else if (w == 0) {
    // exact slow path (wave 0): 64 rounds of wave-reduce max, then index sort
    u64 prev = ~0ull;
    u64 sel = 0;
    for (int r = 0; r < KK; ++r) {
      u64 local = 0;
      for (int tt = 0; tt < LL / 64; ++tt) {
        int l = tt * 64 + lane;
        float v = colp[(size_t)l * CC];
        u64 key = (((u64)flip_bits(__float_as_uint(v))) << 32) | (u32)l;
        if (key < prev) local = u64max(local, key);
      }
#pragma unroll
      for (int mm = 32; mm > 0; mm >>= 1) local = u64max(local, __shfl_xor(local, mm, 64));
      if (lane == r) sel = local;
      prev = local;
    }
    u32 f = (u32)(sel >> 32);
    u32 l = (u32)sel;
    u64 s2 = (((u64)l) << 32) | f;
#pragma unroll
    for (int k = 2; k <= 64; k <<= 1) {
#pragma unroll
      for (int j = k >> 1; j > 0; j >>= 1) {
        u64 other = __shfl_xor(s2, j, 64);
        bool upper = (lane & j) != 0;
        bool ascb = ((lane & k) == 0);
        bool keepmax = ascb ? upper : !upper;
        s2 = keepmax ? u64max(s2, other) : u64min(s2, other);
      }
    }
    out[((size_t)b * KK + lane) * CC + c] = __uint_as_float(unflip_bits((u32)s2));
  }
}

extern "C" void kernel_launch(void* const* d_in, const int* in_sizes, int n_in,
                              void* d_out, int out_size, void* d_ws, size_t ws_size,
                              hipStream_t stream) {
  const float* x = (const float*)d_in[0];
  float* out = (float*)d_out;
  const size_t need = (size_t)BB * LCH * CC * sizeof(u32);  // 8 MB of bitmasks
  if (d_ws != nullptr && ws_size >= need) {
    u32* bm = (u32*)d_ws;
    kbitmask<<<BB * LCH, 128, 0, stream>>>(x, bm);
    kselect<<<BB * CC, 256, 0, stream>>>(x, bm, out, 0);
  } else {
    kselect<<<BB * CC, 256, 0, stream>>>(x, nullptr, out, 1);
  }
}

// Round 15
// 77.641 us; speedup vs baseline: 2.3640x; 1.0303x over previous
//
#include <hip/hip_runtime.h>

typedef unsigned int u32;
typedef unsigned long long u64;

#define BB 16
#define LL 8192
#define CC 512
#define KK 64
#define LCH 256          // L-chunks per batch
#define LPB 32           // rows per chunk (bitmask width)
#define THRESH 2.1f      // survivors/col: mean~146 sigma~12 -> [64,256] w/ ~7 sigma margin

// ---- order-preserving fp32 <-> u32 key transforms ----
__device__ __forceinline__ u32 flip_bits(u32 u) {
  return u ^ ((u & 0x80000000u) ? 0xFFFFFFFFu : 0x80000000u);
}
__device__ __forceinline__ u32 unflip_bits(u32 f) {
  return (f & 0x80000000u) ? (f ^ 0x80000000u) : ~f;
}
__device__ __forceinline__ u64 u64max(u64 a, u64 b) { return a > b ? a : b; }
__device__ __forceinline__ u64 u64min(u64 a, u64 b) { return a < b ? a : b; }

// ---------------- Kernel A (R2-proven, at roofline ~40us): DO NOT TOUCH ----------------
__global__ __launch_bounds__(128) void kbitmask(const float* __restrict__ x,
                                                u32* __restrict__ bm) {
  int blk = blockIdx.x;
  int b = blk >> 8;
  int chunk = blk & (LCH - 1);
  int t = threadIdx.x;
  const float4* p =
      reinterpret_cast<const float4*>(x + ((size_t)b * LL + (size_t)chunk * LPB) * CC) + t;
  u32 m0 = 0, m1 = 0, m2 = 0, m3 = 0;
#pragma unroll
  for (int i = 0; i < LPB; ++i) {
    float4 v = p[(size_t)i * (CC / 4)];
    m0 |= ((u32)(v.x > THRESH)) << i;
    m1 |= ((u32)(v.y > THRESH)) << i;
    m2 |= ((u32)(v.z > THRESH)) << i;
    m3 |= ((u32)(v.w > THRESH)) << i;
  }
  uint4* dst = reinterpret_cast<uint4*>(bm + (size_t)(b * LCH + chunk) * CC) + t;
  *dst = make_uint4(m0, m1, m2, m3);
}

// ---------------- Kernel B: block-per-column + HISTOGRAM select ----------------
// R14 post-mortem: phase-5 rank-by-broadcast was ~45us of serialized LDS-pipe
// issue per CU (146 ds_read_b64/wave x 128 waves/CU). Replaced by O(total)
// 256-bucket histogram on monotone key-top-bits (bits 24:17, values in [2,16)),
// suffix scan, cutoff bucket, tiny boundary-bucket rank. Identical selection
// set; row-order output via unchanged ballot phase. Guards -> exact slow path.
__global__ __launch_bounds__(256) void kselect(const float* __restrict__ x,
                                               const u32* __restrict__ bm,
                                               float* __restrict__ out,
                                               int force_slow) {
  __shared__ u64 wl[256];
  __shared__ u32 wsum[4];
  __shared__ u32 wsum2[4];
  __shared__ u64 selbal[4];
  __shared__ u32 hist[256];
  __shared__ u32 shist[256];
  __shared__ u64 cand[64];
  __shared__ u32 ccnt;
  __shared__ int scb;
  __shared__ int bad;
  int t = threadIdx.x;
  int lane = t & 63;
  int w = t >> 6;
  // XCD-colocating bijection (R14-proven): 16-col line-group -> one XCD's L2
  int bid = blockIdx.x;
  int xcd = bid & 7;
  int iox = bid >> 3;
  int g = (iox >> 4) * 8 + xcd;
  int ch = g * 16 + (iox & 15);
  int b = ch >> 9;
  int c = ch & (CC - 1);
  const float* colp = x + (size_t)b * LL * CC + c;
  const u64 ltmask = (1ull << lane) - 1ull;

  if (t == 0) bad = force_slow;
  wl[t] = 0;
  __syncthreads();

  u32 total = 0;
  if (!force_slow) {
    // phase 1: one mask word per thread
    u32 mw = bm[((size_t)(b * LCH) + (u32)t) * CC + c];
    u32 cnt = __popc(mw);
    // phase 2: block exclusive scan
    u32 inc = cnt;
#pragma unroll
    for (int d = 1; d < 64; d <<= 1) {
      u32 o = __shfl_up(inc, d, 64);
      if (lane >= d) inc += o;
    }
    if (lane == 63) wsum[w] = inc;
    __syncthreads();
    u32 woff = 0;
#pragma unroll
    for (int i = 0; i < 4; ++i) {
      u32 s = wsum[i];
      woff += (i < w) ? s : 0u;
      total += s;
    }
    u32 pos = woff + inc - cnt;
    // phase 3: static 8-slot extraction + one batch of independent NT loads
    u32 rows_[8];
    float vals_[8];
    u32 vbits = 0;
    u32 m = mw;
    u32 base = (u32)t * LPB;
#pragma unroll
    for (int s = 0; s < 8; ++s) {
      u32 bit = __builtin_ctz(m | 0x80000000u);
      vbits |= ((m != 0u) ? 1u : 0u) << s;
      rows_[s] = base + bit;
      m &= m - 1;
    }
    if (m) bad = 1;  // >8 survivors in one word (P ~ 1e-8/word)
#pragma unroll
    for (int s = 0; s < 8; ++s)
      vals_[s] = ((vbits >> s) & 1u)
                     ? __builtin_nontemporal_load(colp + (size_t)rows_[s] * CC)
                     : 0.0f;
    __builtin_amdgcn_sched_barrier(0);
    // phase 4: row-ordered key write
#pragma unroll
    for (int s = 0; s < 8; ++s) {
      if ((vbits >> s) & 1u) {
        if (pos < 256)
          wl[pos] = (((u64)flip_bits(__float_as_uint(vals_[s]))) << 32) | rows_[s];
        else
          bad = 1;
        pos++;
      }
    }
  }
  __syncthreads();

  bool pre_ok = (bad == 0) && total >= (u32)KK && total <= 256u;  // block-uniform
  u64 mykey = 0;
  bool selp = false;
  if (pre_ok) {
    mykey = (t < (int)total) ? wl[t] : 0ull;
    u32 top = (u32)(mykey >> 32);
    u32 mybkt = (top >> 17) & 0xFFu;  // monotone 8-bit bucket for values in [2,16)
    hist[t] = 0;
    if (t == 0) { ccnt = 0; scb = 0; }
    __syncthreads();
    if (t < (int)total) {
      if (top >= 0xC1800000u) bad = 1;  // value >= 16: bucket would wrap
      atomicAdd(&hist[mybkt], 1u);
    }
    __syncthreads();
    // suffix scan: thread t scans bucket rev = 255-t (descending buckets)
    int rev = 255 - t;
    u32 v = hist[rev];
    u32 inc2 = v;
#pragma unroll
    for (int d = 1; d < 64; d <<= 1) {
      u32 o = __shfl_up(inc2, d, 64);
      if (lane >= d) inc2 += o;
    }
    if (lane == 63) wsum2[w] = inc2;
    __syncthreads();
    u32 add = 0;
#pragma unroll
    for (int i = 0; i < 4; ++i) add += (i < w) ? wsum2[i] : 0u;
    shist[rev] = inc2 + add;  // = count of keys with bucket >= rev
    __syncthreads();
    // cutoff bucket: unique t with shist[t] >= KK and shist[t+1] < KK
    u32 s_t = shist[t];
    u32 s_t1 = (t == 255) ? 0u : shist[t + 1];
    if (s_t >= (u32)KK && s_t1 < (u32)KK) scb = t;
    __syncthreads();
    int cb = scb;
    u32 S = (cb == 255) ? 0u : shist[cb + 1];  // definitively selected
    u32 need = (u32)KK - S;                    // >= 1
    bool incb = (t < (int)total) && (mybkt == (u32)cb);
    if (incb) {
      u32 ci = atomicAdd(&ccnt, 1u);
      if (ci < 64u) cand[ci] = mykey;
      else bad = 1;
    }
    __syncthreads();
    u32 rkb = 0;
    if (incb) {
      u32 nc = ccnt > 64u ? 64u : ccnt;
      for (u32 j = 0; j < nc; ++j) rkb += (cand[j] > mykey) ? 1u : 0u;
    }
    selp = (t < (int)total) && ((mybkt > (u32)cb) || (incb && rkb < need));
    __syncthreads();  // make late bad-writes visible
  }

  bool fastok = pre_ok && (bad == 0);
  if (fastok) {
    // phase 6: output position = selected-count before me (wl order = row order)
    u64 bw = __ballot(selp);
    if (lane == 0) selbal[w] = bw;
    __syncthreads();
    if (selp) {
      u32 op = (u32)__popcll(bw & ltmask);
#pragma unroll
      for (int i = 0; i < 4; ++i) op += (i < w) ? (u32)__popcll(selbal[i]) : 0u;
      out[((size_t)b * KK + op) * CC + c] =
          __uint_as_float(unflip_bits((u32)(mykey >> 32)));
    }
  } else if (w == 0) {
    // exact slow path (wave 0): 64 rounds of wave-reduce max, then index sort
    u64 prev = ~0ull;
    u64 sel = 0;
    for (int r = 0; r < KK; ++r) {
      u64 local = 0;
      for (int tt = 0; tt < LL / 64; ++tt) {
        int l = tt * 64 + lane;
        float v = colp[(size_t)l * CC];
        u64 key = (((u64)flip_bits(__float_as_uint(v))) << 32) | (u32)l;
        if (key < prev) local = u64max(local, key);
      }
#pragma unroll
      for (int mm = 32; mm > 0; mm >>= 1) local = u64max(local, __shfl_xor(local, mm, 64));
      if (lane == r) sel = local;
      prev = local;
    }
    u32 f = (u32)(sel >> 32);
    u32 l = (u32)sel;
    u64 s2 = (((u64)l) << 32) | f;
#pragma unroll
    for (int k = 2; k <= 64; k <<= 1) {
#pragma unroll
      for (int j = k >> 1; j > 0; j >>= 1) {
        u64 other = __shfl_xor(s2, j, 64);
        bool upper = (lane & j) != 0;
        bool ascb = ((lane & k) == 0);
        bool keepmax = ascb ? upper : !upper;
        s2 = keepmax ? u64max(s2, other) : u64min(s2, other);
      }
    }
    out[((size_t)b * KK + lane) * CC + c] = __uint_as_float(unflip_bits((u32)s2));
  }
}

extern "C" void kernel_launch(void* const* d_in, const int* in_sizes, int n_in,
                              void* d_out, int out_size, void* d_ws, size_t ws_size,
                              hipStream_t stream) {
  const float* x = (const float*)d_in[0];
  float* out = (float*)d_out;
  const size_t need = (size_t)BB * LCH * CC * sizeof(u32);  // 8 MB of bitmasks
  if (d_ws != nullptr && ws_size >= need) {
    u32* bm = (u32*)d_ws;
    kbitmask<<<BB * LCH, 128, 0, stream>>>(x, bm);
    kselect<<<BB * CC, 256, 0, stream>>>(x, bm, out, 0);
  } else {
    kselect<<<BB * CC, 256, 0, stream>>>(x, nullptr, out, 1);
  }
}